// Round 10
// baseline (406.075 us; speedup 1.0000x reference)
//
#include <hip/hip_runtime.h>
#include <hip/hip_bf16.h>
#include <stdint.h>

typedef __attribute__((ext_vector_type(8))) short short8;
typedef __attribute__((ext_vector_type(4))) float f32x4;
typedef __attribute__((ext_vector_type(16))) float f32x16;
typedef unsigned short ushort_t;

#define VMCNT4 asm volatile("s_waitcnt vmcnt(4)" ::: "memory")
#define VMCNT0 asm volatile("s_waitcnt vmcnt(0)" ::: "memory")
#define LGKM0  asm volatile("s_waitcnt lgkmcnt(0)" ::: "memory")
#define BARRIER asm volatile("s_barrier" ::: "memory")

__device__ inline ushort_t f2bf(float f) {
    union { float f; unsigned u; } v; v.f = f;
    unsigned u = v.u;
    unsigned r = u + 0x7fffu + ((u >> 16) & 1u);
    return (ushort_t)(r >> 16);
}

__device__ inline void gload_lds16(const void* g, void* l) {
    __builtin_amdgcn_global_load_lds((const __attribute__((address_space(1))) void*)g,
                                     (__attribute__((address_space(3))) void*)l,
                                     16, 0, 0);
}

// swizzled LDS frag read: region = 128x64 bf16 row-major (128B rows).
// Guideline-4 swizzle: XOR low 3 row bits into the 16B-slot index (byte bits 4-6).
__device__ inline short8 read_frag(const ushort_t* region, int r, int c) {
    int byte = (r << 7) + (c << 1);
    byte ^= (r & 7) << 4;
    return *(const short8*)((const char*)region + byte);
}

// one 8-MFMA cluster (32x32x16): 2 row-tiles x 4 chained K-chunks into acc[MB..MB+1][NB]
#define MFMA8(AF, MB, NB, BF)                                                     \
    _Pragma("unroll")                                                             \
    for (int mt = 0; mt < 2; ++mt)                                                \
        _Pragma("unroll")                                                         \
        for (int kc = 0; kc < 4; ++kc)                                            \
            acc[(MB) + mt][(NB)] = __builtin_amdgcn_mfma_f32_32x32x16_bf16(       \
                AF[mt * 4 + kc], BF[kc], acc[(MB) + mt][(NB)], 0, 0, 0);

// ---------------- persistent 256x256 GEMM, 32x32x16 MFMA on the R5 skeleton --------
// Same tile geometry / LDS layout / read counts per phase (12/4/8/0) / barriers /
// stages / vmcnt ledger as the proven R5 schedule. Only the MFMA shape changed:
// 32 x v_mfma_f32_32x32x16_bf16 per K-tile (4061 FLOP/cyc) vs 64 x 16x16x32
// (3378 FLOP/cyc) -- 17% fewer MFMA-pipe cycles, half the issue slots.
// A/B frag: row=lane&31, k=(lane>>5)*8+j. C/D: col=lane&31,
// row=(reg&3)+8*(reg>>2)+4*(lane>>5)  [m74/m101 verified layout].
template <int F32OUT>
__global__ __launch_bounds__(512, 2) void gemm256(const ushort_t* __restrict__ A,
                                                  const ushort_t* __restrict__ Bt,
                                                  void* __restrict__ Cc,
                                                  const float* __restrict__ bias,
                                                  int N, int K, int NBN, int LT) {
    __shared__ __align__(16) ushort_t lds[65536];  // 128 KiB
    const int tid = threadIdx.x;
    const int wave = tid >> 6;
    const int lane = tid & 63;
    const int wm = wave >> 2;   // 0..1
    const int wn = wave & 3;    // 0..3
    // pre-swizzled source lane: linear LDS slot = lane&7, row-within-stripe = lane>>3
    const int el = (lane & 56) | ((lane ^ (lane >> 3)) & 7);
    const int NT = K >> 6;      // power of two (16 here)
    const int NTM = NT - 1;

    // XCD-bijective swizzle (LT%8==0) + 8-row supertile rasterization
    auto tile_of = [&](int lt, int& obm, int& obn) {
        int x = (lt & 7) * (LT >> 3) + (lt >> 3);
        int per = NBN << 3;
        int st = x / per;
        int rem = x - st * per;
        obn = rem >> 3;
        obm = (st << 3) + (rem & 7);
    };

    auto STAGE = [&](const ushort_t* g, int rowHalf, int k0, int regionByteOff) {
#pragma unroll
        for (int j = 0; j < 2; ++j) {
            int e = j * 4096 + wave * 512 + el * 8;  // element within 128x64 half
            gload_lds16(g + (size_t)(rowHalf + (e >> 6)) * K + k0 + (e & 63),
                        (char*)lds + regionByteOff + j * 8192 + wave * 1024);
        }
    };

    int bm, bn;
    tile_of((int)blockIdx.x, bm, bn);
    const ushort_t* Ag = A + (size_t)bm * 256 * K;
    const ushort_t* Bg = Bt + (size_t)bn * 256 * K;

    // regions (bytes): A(slot,h) = (slot*2+h)*16384 ; B(slot,h) = 65536 + (slot*2+h)*16384
    // prologue (once per kernel): tile0 K-tile0 (A+B) -> slot0, K-tile1 B -> slot1
    STAGE(Ag, 0,   0, 0);
    STAGE(Ag, 128, 0, 16384);
    STAGE(Bg, 0,   0, 65536);
    STAGE(Bg, 128, 0, 65536 + 16384);
    STAGE(Bg, 0,   64, 65536 + 32768);
    STAGE(Bg, 128, 64, 65536 + 49152);
    VMCNT4;
    BARRIER;

    f32x16 acc[4][2] = {};
    f32x16 zf = {};
    short8 aF[8], aG[8], bF0[4], bF1[4];
    const int rA = lane & 31;            // row within 32-row tile
    const int cK = (lane >> 5) << 3;     // k-offset within 16-chunk
    const int rb = (wn & 1) << 6;

    for (int lt = (int)blockIdx.x; lt < LT; lt += 256) {
        const bool hasN = (lt + 256) < LT;
        int bmN = bm, bnN = bn;
        const ushort_t* AgN = Ag;
        const ushort_t* BgN = Bg;
        if (hasN) {
            tile_of(lt + 256, bmN, bnN);
            AgN = A + (size_t)bmN * 256 * K;
            BgN = Bt + (size_t)bnN * 256 * K;
        }

        for (int it = 0; it < NT; ++it) {
            const int s = it & 1;
            const ushort_t* Ar = lds + ((s << 1) + wm) * 8192;
            const ushort_t* Br = lds + 32768 + ((s << 1) + (wn >> 1)) * 8192;
            const int itA = it + 1, itB = it + 2;
            const bool doA = (itA < NT) || hasN;
            const bool doB = (itB < NT) || hasN;
            const ushort_t* As = (itA < NT) ? Ag : AgN;   // redirect across tile boundary
            const ushort_t* Bs = (itB < NT) ? Bg : BgN;
            const int kA = (itA & NTM) << 6;
            const int kB = (itB & NTM) << 6;
            const int soA = ((s ^ 1) << 1) * 16384;        // other-slot A base
            const int soB = 65536 + (s << 1) * 16384;      // own-slot B base

            // ---- phase 1: reads A row-tiles 0-1 (8) + B col-tile 0 (4); stage A0(next)
#pragma unroll
            for (int mt = 0; mt < 2; ++mt)
#pragma unroll
                for (int kc = 0; kc < 4; ++kc)
                    aF[mt * 4 + kc] = read_frag(Ar, mt * 32 + rA, kc * 16 + cK);
#pragma unroll
            for (int kc = 0; kc < 4; ++kc)
                bF0[kc] = read_frag(Br, rb + rA, kc * 16 + cK);
            if (doA) STAGE(As, 0, kA, soA);
            BARRIER; LGKM0;
            __builtin_amdgcn_s_setprio(1);
            MFMA8(aF, 0, 0, bF0)
            __builtin_amdgcn_s_setprio(0);

            // ---- phase 2: reads B col-tile 1 (4); stage A1(next)
#pragma unroll
            for (int kc = 0; kc < 4; ++kc)
                bF1[kc] = read_frag(Br, rb + 32 + rA, kc * 16 + cK);
            if (doA) STAGE(As, 128, kA, soA + 16384);
            BARRIER; LGKM0;
            __builtin_amdgcn_s_setprio(1);
            MFMA8(aF, 0, 1, bF1)
            __builtin_amdgcn_s_setprio(0);

            // ---- phase 3: reads A row-tiles 2-3 (8); barrier; THEN stage B0(next+1)
#pragma unroll
            for (int mt = 0; mt < 2; ++mt)
#pragma unroll
                for (int kc = 0; kc < 4; ++kc)
                    aG[mt * 4 + kc] = read_frag(Ar, 64 + mt * 32 + rA, kc * 16 + cK);
            BARRIER; LGKM0;
            if (doB) STAGE(Bs, 0, kB, soB);
            __builtin_amdgcn_s_setprio(1);
            MFMA8(aG, 2, 0, bF0)
            __builtin_amdgcn_s_setprio(0);

            // ---- phase 4: stage B1(next+1); MFMA; vmcnt checkpoint; tile-end barrier
            if (doB) STAGE(Bs, 128, kB, soB + 16384);
            __builtin_amdgcn_s_setprio(1);
            MFMA8(aG, 2, 1, bF1)
            __builtin_amdgcn_s_setprio(0);
            if (doB) { VMCNT4; } else { VMCNT0; }
            BARRIER;
        }

        // ---- epilogue for (bm,bn): 32x32 C/D layout, stores overlap next tile
        const int row0 = bm * 256 + wm * 128 + ((lane >> 5) << 2);
        const int col0 = bn * 256 + wn * 64 + (lane & 31);
#pragma unroll
        for (int mb = 0; mb < 4; ++mb) {
#pragma unroll
            for (int nb = 0; nb < 2; ++nb) {
                const int col = col0 + nb * 32;
                f32x16 v = acc[mb][nb];
                if constexpr (F32OUT) {
                    float bz = bias[col];
                    float* C = (float*)Cc;
#pragma unroll
                    for (int g = 0; g < 4; ++g)
#pragma unroll
                        for (int q = 0; q < 4; ++q)
                            C[(size_t)(row0 + mb * 32 + g * 8 + q) * N + col] = v[g * 4 + q] + bz;
                } else {
                    ushort_t* C = (ushort_t*)Cc;
#pragma unroll
                    for (int g = 0; g < 4; ++g)
#pragma unroll
                        for (int q = 0; q < 4; ++q)
                            C[(size_t)(row0 + mb * 32 + g * 8 + q) * N + col] = f2bf(v[g * 4 + q]);
                }
                acc[mb][nb] = zf;
            }
        }
        Ag = AgN; Bg = BgN; bm = bmN; bn = bnN;
    }
}

// ---------------- merged prep: cast_x (blocks 0..2047) + transpose wqkv (2048..2815)
//                  + transpose wproj (2816..3071), one dispatch ----------------
__global__ __launch_bounds__(256) void prep_kernel(const float* __restrict__ x,
                                                   ushort_t* __restrict__ x_bf,
                                                   const float* __restrict__ w_qkv,
                                                   ushort_t* __restrict__ wq_t,
                                                   const float* __restrict__ w_proj,
                                                   ushort_t* __restrict__ wp_t) {
    const int blk = blockIdx.x;
    const int t = threadIdx.x;
    if (blk < 2048) {
        const int n8 = 33554432 / 8;
        int i = blk * 256 + t;
        const int stride = 2048 * 256;
        for (; i < n8; i += stride) {
            const float4* p = (const float4*)(x + (size_t)i * 8);
            float4 a = p[0];
            float4 b = p[1];
            uint4 w;
            w.x = (unsigned)f2bf(a.x) | ((unsigned)f2bf(a.y) << 16);
            w.y = (unsigned)f2bf(a.z) | ((unsigned)f2bf(a.w) << 16);
            w.z = (unsigned)f2bf(b.x) | ((unsigned)f2bf(b.y) << 16);
            w.w = (unsigned)f2bf(b.z) | ((unsigned)f2bf(b.w) << 16);
            *(uint4*)(x_bf + (size_t)i * 8) = w;
        }
        return;
    }
    const float* in;
    ushort_t* out;
    int Cn, c0, r0;
    if (blk < 2048 + 768) {
        int id = blk - 2048;           // wqkv: 48 x 16
        in = w_qkv; out = wq_t; Cn = 3072;
        c0 = (id % 48) * 64; r0 = (id / 48) * 64;
    } else {
        int id = blk - 2048 - 768;     // wproj: 16 x 16
        in = w_proj; out = wp_t; Cn = 1024;
        c0 = (id % 16) * 64; r0 = (id / 16) * 64;
    }
    __shared__ float tile[64][65];
    int lr = t >> 4;
    int lc = (t & 15) * 4;
#pragma unroll
    for (int i = 0; i < 4; i++) {
        const float* src = in + (size_t)(r0 + i * 16 + lr) * Cn + c0 + lc;
        float4 v = *(const float4*)src;
        tile[i * 16 + lr][lc + 0] = v.x;
        tile[i * 16 + lr][lc + 1] = v.y;
        tile[i * 16 + lr][lc + 2] = v.z;
        tile[i * 16 + lr][lc + 3] = v.w;
    }
    __syncthreads();
    int oc = t >> 4;
    int ok = (t & 15) * 4;
#pragma unroll
    for (int i = 0; i < 4; i++) {
        int c = c0 + i * 16 + oc;
        ushort4 w;
        w.x = f2bf(tile[ok + 0][i * 16 + oc]);
        w.y = f2bf(tile[ok + 1][i * 16 + oc]);
        w.z = f2bf(tile[ok + 2][i * 16 + oc]);
        w.w = f2bf(tile[ok + 3][i * 16 + oc]);
        *(ushort4*)(out + (size_t)c * 1024 + r0 + ok) = w;
    }
}

// ---------------- per-token head-mixing attention (exact R5/R9 state) ----------------
__global__ __launch_bounds__(256) void attn_kernel(const ushort_t* __restrict__ qkv,
                                                   ushort_t* __restrict__ operm) {
    __shared__ __align__(16) float plds[4][16 * 20];
    const int wave = threadIdx.x >> 6;
    const int lane = threadIdx.x & 63;
    float* P = plds[wave];
    const int fr = lane & 15;
    const int fo = (lane >> 4) * 8;
    int tok = (blockIdx.x * 4 + wave) * 4;
    for (int it = 0; it < 4; it++, tok++) {
        const ushort_t* row = qkv + (size_t)tok * 3072;
        short8 aq0 = *(const short8*)(row + fr * 64 + fo);
        short8 aq1 = *(const short8*)(row + fr * 64 + 32 + fo);
        short8 bk0 = *(const short8*)(row + 1024 + fr * 64 + fo);
        short8 bk1 = *(const short8*)(row + 1024 + fr * 64 + 32 + fo);
        f32x4 s = {0.f, 0.f, 0.f, 0.f};
        s = __builtin_amdgcn_mfma_f32_16x16x32_bf16(aq0, bk0, s, 0, 0, 0);
        s = __builtin_amdgcn_mfma_f32_16x16x32_bf16(aq1, bk1, s, 0, 0, 0);
        float ls[4], m[4], p[4], sm[4];
#pragma unroll
        for (int q = 0; q < 4; q++) { ls[q] = s[q] * 0.125f; m[q] = ls[q]; }
#pragma unroll
        for (int d = 1; d < 16; d <<= 1)
#pragma unroll
            for (int q = 0; q < 4; q++) m[q] = fmaxf(m[q], __shfl_xor(m[q], d));
#pragma unroll
        for (int q = 0; q < 4; q++) { p[q] = __expf(ls[q] - m[q]); sm[q] = p[q]; }
#pragma unroll
        for (int d = 1; d < 16; d <<= 1)
#pragma unroll
            for (int q = 0; q < 4; q++) sm[q] += __shfl_xor(sm[q], d);
#pragma unroll
        for (int q = 0; q < 4; q++) P[((lane >> 4) * 4 + q) * 20 + fr] = p[q];
        __syncthreads();
        short8 pa = {};
        if (lane < 32) {
            const float* src = P + fr * 20 + fo;
            float4 r0 = *(const float4*)src;
            float4 r1 = *(const float4*)(src + 4);
            pa[0] = (short)f2bf(r0.x); pa[1] = (short)f2bf(r0.y);
            pa[2] = (short)f2bf(r0.z); pa[3] = (short)f2bf(r0.w);
            pa[4] = (short)f2bf(r1.x); pa[5] = (short)f2bf(r1.y);
            pa[6] = (short)f2bf(r1.z); pa[7] = (short)f2bf(r1.w);
        }
        __syncthreads();
        f32x4 o[4] = {};
        const ushort_t* vrow = row + 2048;
#pragma unroll
        for (int db = 0; db < 4; db++) {
            short8 bv = {};
            if (lane < 32) {
#pragma unroll
                for (int j = 0; j < 8; j++)
                    bv[j] = (short)vrow[(fo + j) * 64 + db * 16 + fr];
            }
            o[db] = __builtin_amdgcn_mfma_f32_16x16x32_bf16(pa, bv, o[db], 0, 0, 0);
        }
        float inv[4];
#pragma unroll
        for (int q = 0; q < 4; q++) inv[q] = 1.0f / sm[q];
        int b = tok >> 12;
        int n = tok & 4095;
        ushort_t* obase = operm + ((size_t)b << 22);
        int rlo = n >> 4;
        int cbase = (n & 15) * 64;
#pragma unroll
        for (int db = 0; db < 4; db++) {
#pragma unroll
            for (int q = 0; q < 4; q++) {
                int h = (lane >> 4) * 4 + q;
                int d = db * 16 + fr;
                obase[(size_t)(h * 256 + rlo) * 1024 + cbase + d] = f2bf(o[db][q] * inv[q]);
            }
        }
    }
}

extern "C" void kernel_launch(void* const* d_in, const int* in_sizes, int n_in,
                              void* d_out, int out_size, void* d_ws, size_t ws_size,
                              hipStream_t stream) {
    const float* x = (const float*)d_in[0];
    const float* w_qkv = (const float*)d_in[1];
    const float* w_proj = (const float*)d_in[2];
    const float* b_proj = (const float*)d_in[3];
    float* out = (float*)d_out;

    char* ws = (char*)d_ws;
    ushort_t* x_bf  = (ushort_t*)(ws);                  //  64 MiB: [32768][1024]
    ushort_t* wq_t  = (ushort_t*)(ws + 67108864);       //   6 MiB: [3072][1024]
    ushort_t* wp_t  = (ushort_t*)(ws + 73400320);       //   2 MiB: [1024][1024]
    ushort_t* qkv   = (ushort_t*)(ws + 75497472);       // 192 MiB: [32768][3072]
    ushort_t* operm = (ushort_t*)(ws + 276824064);      //  64 MiB: [32768][1024]

    prep_kernel<<<3072, 256, 0, stream>>>(x, x_bf, w_qkv, wq_t, w_proj, wp_t);
    gemm256<0><<<256, 512, 0, stream>>>(x_bf, wq_t, qkv, nullptr, 3072, 1024, 12, 1536);
    attn_kernel<<<2048, 256, 0, stream>>>(qkv, operm);
    gemm256<1><<<256, 512, 0, stream>>>(operm, wp_t, out, b_proj, 1024, 1024, 4, 512);
}

// Round 11
// 375.884 us; speedup vs baseline: 1.0803x; 1.0803x over previous
//
#include <hip/hip_runtime.h>
#include <hip/hip_bf16.h>
#include <stdint.h>

typedef __attribute__((ext_vector_type(8))) short short8;
typedef __attribute__((ext_vector_type(4))) float f32x4;
typedef unsigned short ushort_t;

#define VMCNT4 asm volatile("s_waitcnt vmcnt(4)" ::: "memory")
#define VMCNT0 asm volatile("s_waitcnt vmcnt(0)" ::: "memory")
#define LGKM0  asm volatile("s_waitcnt lgkmcnt(0)" ::: "memory")
#define BARRIER asm volatile("s_barrier" ::: "memory")

__device__ inline ushort_t f2bf(float f) {
    union { float f; unsigned u; } v; v.f = f;
    unsigned u = v.u;
    unsigned r = u + 0x7fffu + ((u >> 16) & 1u);
    return (ushort_t)(r >> 16);
}

__device__ inline void gload_lds16(const void* g, void* l) {
    __builtin_amdgcn_global_load_lds((const __attribute__((address_space(1))) void*)g,
                                     (__attribute__((address_space(3))) void*)l,
                                     16, 0, 0);
}

// swizzled LDS frag read: region = 128x64 bf16 row-major (128B rows).
// Guideline-4 swizzle: XOR low 3 row bits into the 16B-slot index (byte bits 4-6).
__device__ inline short8 read_frag(const ushort_t* region, int r, int c) {
    int byte = (r << 7) + (c << 1);
    byte ^= (r & 7) << 4;
    return *(const short8*)((const char*)region + byte);
}

// one 16-MFMA cluster: acc[MB..MB+3][NB..NB+1] += AF x BF
#define MFMA16(AF, MB, NB, BF)                                                    \
    _Pragma("unroll")                                                             \
    for (int mi = 0; mi < 4; ++mi)                                                \
        _Pragma("unroll")                                                         \
        for (int ni = 0; ni < 2; ++ni)                                            \
            _Pragma("unroll")                                                     \
            for (int ks = 0; ks < 2; ++ks)                                        \
                acc[(MB) + mi][(NB) + ni] = __builtin_amdgcn_mfma_f32_16x16x32_bf16( \
                    AF[mi * 2 + ks], BF[ni * 2 + ks], acc[(MB) + mi][(NB) + ni], 0, 0, 0);

// ---------------- persistent 256x256 GEMM (exact R9 state, best measured) ----------
// 8 waves (2M x 4N), BK=64, 128 KiB LDS, row&7 XOR swizzle, 4 barriers/tile,
// persistent blocks with cross-tile staging redirect. R6-R8: any reordering of
// reads/stages/waits breaks hipcc codegen. R10: 32x32 MFMA re-introduces bank
// conflicts (1.9e7) for zero net gain. Frozen.
template <int F32OUT>
__global__ __launch_bounds__(512, 2) void gemm256(const ushort_t* __restrict__ A,
                                                  const ushort_t* __restrict__ Bt,
                                                  void* __restrict__ Cc,
                                                  const float* __restrict__ bias,
                                                  int N, int K, int NBN, int LT) {
    __shared__ __align__(16) ushort_t lds[65536];  // 128 KiB
    const int tid = threadIdx.x;
    const int wave = tid >> 6;
    const int lane = tid & 63;
    const int wm = wave >> 2;   // 0..1
    const int wn = wave & 3;    // 0..3
    const int el = (lane & 56) | ((lane ^ (lane >> 3)) & 7);
    const int NT = K >> 6;
    const int NTM = NT - 1;

    auto tile_of = [&](int lt, int& obm, int& obn) {
        int x = (lt & 7) * (LT >> 3) + (lt >> 3);
        int per = NBN << 3;
        int st = x / per;
        int rem = x - st * per;
        obn = rem >> 3;
        obm = (st << 3) + (rem & 7);
    };

    auto STAGE = [&](const ushort_t* g, int rowHalf, int k0, int regionByteOff) {
#pragma unroll
        for (int j = 0; j < 2; ++j) {
            int e = j * 4096 + wave * 512 + el * 8;
            gload_lds16(g + (size_t)(rowHalf + (e >> 6)) * K + k0 + (e & 63),
                        (char*)lds + regionByteOff + j * 8192 + wave * 1024);
        }
    };

    int bm, bn;
    tile_of((int)blockIdx.x, bm, bn);
    const ushort_t* Ag = A + (size_t)bm * 256 * K;
    const ushort_t* Bg = Bt + (size_t)bn * 256 * K;

    STAGE(Ag, 0,   0, 0);
    STAGE(Ag, 128, 0, 16384);
    STAGE(Bg, 0,   0, 65536);
    STAGE(Bg, 128, 0, 65536 + 16384);
    STAGE(Bg, 0,   64, 65536 + 32768);
    STAGE(Bg, 128, 64, 65536 + 49152);
    VMCNT4;
    BARRIER;

    f32x4 acc[8][4] = {};
    short8 aF[8], aG[8], bF0[4], bF1[4];
    const f32x4 zf = {0.f, 0.f, 0.f, 0.f};
    const int ra = lane & 15;
    const int ca = (lane >> 4) << 3;
    const int rb = (wn & 1) << 6;

    for (int lt = (int)blockIdx.x; lt < LT; lt += 256) {
        const bool hasN = (lt + 256) < LT;
        int bmN = bm, bnN = bn;
        const ushort_t* AgN = Ag;
        const ushort_t* BgN = Bg;
        if (hasN) {
            tile_of(lt + 256, bmN, bnN);
            AgN = A + (size_t)bmN * 256 * K;
            BgN = Bt + (size_t)bnN * 256 * K;
        }

        for (int it = 0; it < NT; ++it) {
            const int s = it & 1;
            const ushort_t* Ar = lds + ((s << 1) + wm) * 8192;
            const ushort_t* Br = lds + 32768 + ((s << 1) + (wn >> 1)) * 8192;
            const int itA = it + 1, itB = it + 2;
            const bool doA = (itA < NT) || hasN;
            const bool doB = (itB < NT) || hasN;
            const ushort_t* As = (itA < NT) ? Ag : AgN;
            const ushort_t* Bs = (itB < NT) ? Bg : BgN;
            const int kA = (itA & NTM) << 6;
            const int kB = (itB & NTM) << 6;
            const int soA = ((s ^ 1) << 1) * 16384;
            const int soB = 65536 + (s << 1) * 16384;

            // ---- phase 1
#pragma unroll
            for (int mi = 0; mi < 4; ++mi)
#pragma unroll
                for (int ks = 0; ks < 2; ++ks)
                    aF[mi * 2 + ks] = read_frag(Ar, mi * 16 + ra, ks * 32 + ca);
#pragma unroll
            for (int ni = 0; ni < 2; ++ni)
#pragma unroll
                for (int ks = 0; ks < 2; ++ks)
                    bF0[ni * 2 + ks] = read_frag(Br, rb + ni * 16 + ra, ks * 32 + ca);
            if (doA) STAGE(As, 0, kA, soA);
            BARRIER; LGKM0;
            __builtin_amdgcn_s_setprio(1);
            MFMA16(aF, 0, 0, bF0)
            __builtin_amdgcn_s_setprio(0);

            // ---- phase 2
#pragma unroll
            for (int ni = 0; ni < 2; ++ni)
#pragma unroll
                for (int ks = 0; ks < 2; ++ks)
                    bF1[ni * 2 + ks] = read_frag(Br, rb + 32 + ni * 16 + ra, ks * 32 + ca);
            if (doA) STAGE(As, 128, kA, soA + 16384);
            BARRIER; LGKM0;
            __builtin_amdgcn_s_setprio(1);
            MFMA16(aF, 0, 2, bF1)
            __builtin_amdgcn_s_setprio(0);

            // ---- phase 3
#pragma unroll
            for (int mi = 0; mi < 4; ++mi)
#pragma unroll
                for (int ks = 0; ks < 2; ++ks)
                    aG[mi * 2 + ks] = read_frag(Ar, 64 + mi * 16 + ra, ks * 32 + ca);
            BARRIER; LGKM0;
            if (doB) STAGE(Bs, 0, kB, soB);
            __builtin_amdgcn_s_setprio(1);
            MFMA16(aG, 4, 0, bF0)
            __builtin_amdgcn_s_setprio(0);

            // ---- phase 4
            if (doB) STAGE(Bs, 128, kB, soB + 16384);
            __builtin_amdgcn_s_setprio(1);
            MFMA16(aG, 4, 2, bF1)
            __builtin_amdgcn_s_setprio(0);
            if (doB) { VMCNT4; } else { VMCNT0; }
            BARRIER;
        }

        const int row0 = bm * 256 + wm * 128 + (lane >> 4) * 4;
        const int col0 = bn * 256 + wn * 64 + (lane & 15);
#pragma unroll
        for (int mi = 0; mi < 8; ++mi) {
#pragma unroll
            for (int ni = 0; ni < 4; ++ni) {
                const int col = col0 + ni * 16;
                f32x4 v = acc[mi][ni];
                if constexpr (F32OUT) {
                    float bz = bias[col];
                    float* C = (float*)Cc;
#pragma unroll
                    for (int q = 0; q < 4; ++q)
                        C[(size_t)(row0 + mi * 16 + q) * N + col] = v[q] + bz;
                } else {
                    ushort_t* C = (ushort_t*)Cc;
#pragma unroll
                    for (int q = 0; q < 4; ++q)
                        C[(size_t)(row0 + mi * 16 + q) * N + col] = f2bf(v[q]);
                }
                acc[mi][ni] = zf;
            }
        }
        Ag = AgN; Bg = BgN; bm = bmN; bn = bnN;
    }
}

// ---------------- merged prep (unchanged from R9) ----------------
__global__ __launch_bounds__(256) void prep_kernel(const float* __restrict__ x,
                                                   ushort_t* __restrict__ x_bf,
                                                   const float* __restrict__ w_qkv,
                                                   ushort_t* __restrict__ wq_t,
                                                   const float* __restrict__ w_proj,
                                                   ushort_t* __restrict__ wp_t) {
    const int blk = blockIdx.x;
    const int t = threadIdx.x;
    if (blk < 2048) {
        const int n8 = 33554432 / 8;
        int i = blk * 256 + t;
        const int stride = 2048 * 256;
        for (; i < n8; i += stride) {
            const float4* p = (const float4*)(x + (size_t)i * 8);
            float4 a = p[0];
            float4 b = p[1];
            uint4 w;
            w.x = (unsigned)f2bf(a.x) | ((unsigned)f2bf(a.y) << 16);
            w.y = (unsigned)f2bf(a.z) | ((unsigned)f2bf(a.w) << 16);
            w.z = (unsigned)f2bf(b.x) | ((unsigned)f2bf(b.y) << 16);
            w.w = (unsigned)f2bf(b.z) | ((unsigned)f2bf(b.w) << 16);
            *(uint4*)(x_bf + (size_t)i * 8) = w;
        }
        return;
    }
    const float* in;
    ushort_t* out;
    int Cn, c0, r0;
    if (blk < 2048 + 768) {
        int id = blk - 2048;
        in = w_qkv; out = wq_t; Cn = 3072;
        c0 = (id % 48) * 64; r0 = (id / 48) * 64;
    } else {
        int id = blk - 2048 - 768;
        in = w_proj; out = wp_t; Cn = 1024;
        c0 = (id % 16) * 64; r0 = (id / 16) * 64;
    }
    __shared__ float tile[64][65];
    int lr = t >> 4;
    int lc = (t & 15) * 4;
#pragma unroll
    for (int i = 0; i < 4; i++) {
        const float* src = in + (size_t)(r0 + i * 16 + lr) * Cn + c0 + lc;
        float4 v = *(const float4*)src;
        tile[i * 16 + lr][lc + 0] = v.x;
        tile[i * 16 + lr][lc + 1] = v.y;
        tile[i * 16 + lr][lc + 2] = v.z;
        tile[i * 16 + lr][lc + 3] = v.w;
    }
    __syncthreads();
    int oc = t >> 4;
    int ok = (t & 15) * 4;
#pragma unroll
    for (int i = 0; i < 4; i++) {
        int c = c0 + i * 16 + oc;
        ushort4 w;
        w.x = f2bf(tile[ok + 0][i * 16 + oc]);
        w.y = f2bf(tile[ok + 1][i * 16 + oc]);
        w.z = f2bf(tile[ok + 2][i * 16 + oc]);
        w.w = f2bf(tile[ok + 3][i * 16 + oc]);
        *(ushort4*)(out + (size_t)c * 1024 + r0 + ok) = w;
    }
}

// ---------------- per-token head-mixing attention, vectorized V + O paths ----------
// V staged via per-wave swizzled LDS: slot(d,gh) = (2d+gh) ^ 2*(d>>4); 16B slots.
//  - write: 64 lanes x 2 short8 global loads + 16 ds_write_b16 (<=2-way bank)
//  - read:  PV B-frag = ONE aligned ds_read_b128 per db (was 32 scalar global loads)
// O bounced through [16][72] LDS -> 2 coalesced short8 global stores (was 16 scalars).
// All buffers wave-private; wave-local lgkmcnt(0) ordering (DS pipe in-order/wave).
__global__ __launch_bounds__(256) void attn_kernel(const ushort_t* __restrict__ qkv,
                                                   ushort_t* __restrict__ operm) {
    __shared__ __align__(16) ushort_t vtl[4][1024];   // 128 slots x 8 ushort / wave
    __shared__ __align__(16) float pl[4][16 * 20];
    __shared__ __align__(16) ushort_t oll[4][16 * 72];
    const int wave = threadIdx.x >> 6;
    const int lane = threadIdx.x & 63;
    ushort_t* VT = vtl[wave];
    float* P = pl[wave];
    ushort_t* OL = oll[wave];
    const int fr = lane & 15;
    const int hs = lane >> 4;          // 0..3
    const int fo = hs * 8;
    const int vg = lane & 15;          // V-stage: g row
    const int vdq = lane >> 4;         // V-stage: d quarter (0..3)
    const int oh = lane >> 2;          // O-readback: h row
    const int od = (lane & 3) * 16;    // O-readback: d base
    int tok = (blockIdx.x * 4 + wave) * 4;
    for (int it = 0; it < 4; it++, tok++) {
        const ushort_t* row = qkv + (size_t)tok * 3072;
        short8 aq0 = *(const short8*)(row + fr * 64 + fo);
        short8 aq1 = *(const short8*)(row + fr * 64 + 32 + fo);
        short8 bk0 = *(const short8*)(row + 1024 + fr * 64 + fo);
        short8 bk1 = *(const short8*)(row + 1024 + fr * 64 + 32 + fo);
        short8 v0 = *(const short8*)(row + 2048 + vg * 64 + vdq * 16);
        short8 v1 = *(const short8*)(row + 2048 + vg * 64 + vdq * 16 + 8);
        f32x4 s = {0.f, 0.f, 0.f, 0.f};
        s = __builtin_amdgcn_mfma_f32_16x16x32_bf16(aq0, bk0, s, 0, 0, 0);
        s = __builtin_amdgcn_mfma_f32_16x16x32_bf16(aq1, bk1, s, 0, 0, 0);
        // V -> VT (swizzled), overlaps softmax below
#pragma unroll
        for (int j = 0; j < 8; ++j) {
            int d = vdq * 16 + j;
            int slot = (2 * d + (vg >> 3)) ^ (2 * vdq);
            VT[slot * 8 + (vg & 7)] = (ushort_t)v0[j];
        }
#pragma unroll
        for (int j = 0; j < 8; ++j) {
            int d = vdq * 16 + 8 + j;
            int slot = (2 * d + (vg >> 3)) ^ (2 * vdq);
            VT[slot * 8 + (vg & 7)] = (ushort_t)v1[j];
        }
        float ls[4], m[4], p[4], sm[4];
#pragma unroll
        for (int q = 0; q < 4; q++) { ls[q] = s[q] * 0.125f; m[q] = ls[q]; }
#pragma unroll
        for (int d = 1; d < 16; d <<= 1)
#pragma unroll
            for (int q = 0; q < 4; q++) m[q] = fmaxf(m[q], __shfl_xor(m[q], d));
#pragma unroll
        for (int q = 0; q < 4; q++) { p[q] = __expf(ls[q] - m[q]); sm[q] = p[q]; }
#pragma unroll
        for (int d = 1; d < 16; d <<= 1)
#pragma unroll
            for (int q = 0; q < 4; q++) sm[q] += __shfl_xor(sm[q], d);
#pragma unroll
        for (int q = 0; q < 4; q++) P[(hs * 4 + q) * 20 + fr] = p[q];
        LGKM0;  // VT + P writes complete (wave-local; DS in-order per wave)
        short8 pa = {};
        short8 bv[4] = {};
        if (lane < 32) {
            const float* src = P + fr * 20 + fo;
            float4 r0 = *(const float4*)src;
            float4 r1 = *(const float4*)(src + 4);
            pa[0] = (short)f2bf(r0.x); pa[1] = (short)f2bf(r0.y);
            pa[2] = (short)f2bf(r0.z); pa[3] = (short)f2bf(r0.w);
            pa[4] = (short)f2bf(r1.x); pa[5] = (short)f2bf(r1.y);
            pa[6] = (short)f2bf(r1.z); pa[7] = (short)f2bf(r1.w);
#pragma unroll
            for (int db = 0; db < 4; ++db) {
                int d = db * 16 + fr;
                int slot = (2 * d + hs) ^ (2 * db);
                bv[db] = *(const short8*)(VT + slot * 8);
            }
        }
        f32x4 o[4] = {};
#pragma unroll
        for (int db = 0; db < 4; db++)
            o[db] = __builtin_amdgcn_mfma_f32_16x16x32_bf16(pa, bv[db], o[db], 0, 0, 0);
        float inv[4];
#pragma unroll
        for (int q = 0; q < 4; q++) inv[q] = 1.0f / sm[q];
        // O -> OL [16][72] -> coalesced stores
#pragma unroll
        for (int db = 0; db < 4; db++)
#pragma unroll
            for (int q = 0; q < 4; q++)
                OL[(hs * 4 + q) * 72 + db * 16 + fr] = f2bf(o[db][q] * inv[q]);
        LGKM0;  // OL writes complete
        int b = tok >> 12;
        int n = tok & 4095;
        short8 w0 = *(const short8*)(OL + oh * 72 + od);
        short8 w1 = *(const short8*)(OL + oh * 72 + od + 8);
        ushort_t* dst = operm + ((size_t)b << 22)
                      + ((size_t)(oh * 256 + (n >> 4))) * 1024 + (n & 15) * 64 + od;
        *(short8*)dst = w0;
        *(short8*)(dst + 8) = w1;
        LGKM0;  // OL/VT reads drained before next token's writes (WAR, wave-local)
    }
}

extern "C" void kernel_launch(void* const* d_in, const int* in_sizes, int n_in,
                              void* d_out, int out_size, void* d_ws, size_t ws_size,
                              hipStream_t stream) {
    const float* x = (const float*)d_in[0];
    const float* w_qkv = (const float*)d_in[1];
    const float* w_proj = (const float*)d_in[2];
    const float* b_proj = (const float*)d_in[3];
    float* out = (float*)d_out;

    char* ws = (char*)d_ws;
    ushort_t* x_bf  = (ushort_t*)(ws);                  //  64 MiB: [32768][1024]
    ushort_t* wq_t  = (ushort_t*)(ws + 67108864);       //   6 MiB: [3072][1024]
    ushort_t* wp_t  = (ushort_t*)(ws + 73400320);       //   2 MiB: [1024][1024]
    ushort_t* qkv   = (ushort_t*)(ws + 75497472);       // 192 MiB: [32768][3072]
    ushort_t* operm = (ushort_t*)(ws + 276824064);      //  64 MiB: [32768][1024]

    prep_kernel<<<3072, 256, 0, stream>>>(x, x_bf, w_qkv, wq_t, w_proj, wp_t);
    gemm256<0><<<256, 512, 0, stream>>>(x_bf, wq_t, qkv, nullptr, 3072, 1024, 12, 1536);
    attn_kernel<<<2048, 256, 0, stream>>>(qkv, operm);
    gemm256<1><<<256, 512, 0, stream>>>(operm, wp_t, out, b_proj, 1024, 1024, 4, 512);
}

// Round 12
// 375.618 us; speedup vs baseline: 1.0811x; 1.0007x over previous
//
#include <hip/hip_runtime.h>
#include <hip/hip_bf16.h>
#include <stdint.h>

typedef __attribute__((ext_vector_type(8))) short short8;
typedef __attribute__((ext_vector_type(4))) float f32x4;
typedef unsigned short ushort_t;

#define VMCNT4 asm volatile("s_waitcnt vmcnt(4)" ::: "memory")
#define VMCNT0 asm volatile("s_waitcnt vmcnt(0)" ::: "memory")
#define LGKM0  asm volatile("s_waitcnt lgkmcnt(0)" ::: "memory")
#define BARRIER asm volatile("s_barrier" ::: "memory")

__device__ inline ushort_t f2bf(float f) {
    union { float f; unsigned u; } v; v.f = f;
    unsigned u = v.u;
    unsigned r = u + 0x7fffu + ((u >> 16) & 1u);
    return (ushort_t)(r >> 16);
}

__device__ inline void gload_lds16(const void* g, void* l) {
    __builtin_amdgcn_global_load_lds((const __attribute__((address_space(1))) void*)g,
                                     (__attribute__((address_space(3))) void*)l,
                                     16, 0, 0);
}

// swizzled LDS frag read: region = 128x64 bf16 row-major (128B rows).
// Guideline-4 swizzle: XOR low 3 row bits into the 16B-slot index (byte bits 4-6).
__device__ inline short8 read_frag(const ushort_t* region, int r, int c) {
    int byte = (r << 7) + (c << 1);
    byte ^= (r & 7) << 4;
    return *(const short8*)((const char*)region + byte);
}

// one 16-MFMA cluster: acc[MB..MB+3][NB..NB+1] += AF x BF
#define MFMA16(AF, MB, NB, BF)                                                    \
    _Pragma("unroll")                                                             \
    for (int mi = 0; mi < 4; ++mi)                                                \
        _Pragma("unroll")                                                         \
        for (int ni = 0; ni < 2; ++ni)                                            \
            _Pragma("unroll")                                                     \
            for (int ks = 0; ks < 2; ++ks)                                        \
                acc[(MB) + mi][(NB) + ni] = __builtin_amdgcn_mfma_f32_16x16x32_bf16( \
                    AF[mi * 2 + ks], BF[ni * 2 + ks], acc[(MB) + mi][(NB) + ni], 0, 0, 0);

// ---------------- persistent 256x256 GEMM (exact R9/R11 state, best measured) -------
// 8 waves (2M x 4N), BK=64, 128 KiB LDS, row&7 XOR swizzle, 4 barriers/tile,
// persistent blocks with cross-tile staging redirect. R6-R8: any reordering of
// reads/stages/waits breaks hipcc codegen. R10: 32x32 MFMA re-introduces bank
// conflicts for zero net gain. Frozen.
template <int F32OUT>
__global__ __launch_bounds__(512, 2) void gemm256(const ushort_t* __restrict__ A,
                                                  const ushort_t* __restrict__ Bt,
                                                  void* __restrict__ Cc,
                                                  const float* __restrict__ bias,
                                                  int N, int K, int NBN, int LT) {
    __shared__ __align__(16) ushort_t lds[65536];  // 128 KiB
    const int tid = threadIdx.x;
    const int wave = tid >> 6;
    const int lane = tid & 63;
    const int wm = wave >> 2;   // 0..1
    const int wn = wave & 3;    // 0..3
    const int el = (lane & 56) | ((lane ^ (lane >> 3)) & 7);
    const int NT = K >> 6;
    const int NTM = NT - 1;

    auto tile_of = [&](int lt, int& obm, int& obn) {
        int x = (lt & 7) * (LT >> 3) + (lt >> 3);
        int per = NBN << 3;
        int st = x / per;
        int rem = x - st * per;
        obn = rem >> 3;
        obm = (st << 3) + (rem & 7);
    };

    auto STAGE = [&](const ushort_t* g, int rowHalf, int k0, int regionByteOff) {
#pragma unroll
        for (int j = 0; j < 2; ++j) {
            int e = j * 4096 + wave * 512 + el * 8;
            gload_lds16(g + (size_t)(rowHalf + (e >> 6)) * K + k0 + (e & 63),
                        (char*)lds + regionByteOff + j * 8192 + wave * 1024);
        }
    };

    int bm, bn;
    tile_of((int)blockIdx.x, bm, bn);
    const ushort_t* Ag = A + (size_t)bm * 256 * K;
    const ushort_t* Bg = Bt + (size_t)bn * 256 * K;

    STAGE(Ag, 0,   0, 0);
    STAGE(Ag, 128, 0, 16384);
    STAGE(Bg, 0,   0, 65536);
    STAGE(Bg, 128, 0, 65536 + 16384);
    STAGE(Bg, 0,   64, 65536 + 32768);
    STAGE(Bg, 128, 64, 65536 + 49152);
    VMCNT4;
    BARRIER;

    f32x4 acc[8][4] = {};
    short8 aF[8], aG[8], bF0[4], bF1[4];
    const f32x4 zf = {0.f, 0.f, 0.f, 0.f};
    const int ra = lane & 15;
    const int ca = (lane >> 4) << 3;
    const int rb = (wn & 1) << 6;

    for (int lt = (int)blockIdx.x; lt < LT; lt += 256) {
        const bool hasN = (lt + 256) < LT;
        int bmN = bm, bnN = bn;
        const ushort_t* AgN = Ag;
        const ushort_t* BgN = Bg;
        if (hasN) {
            tile_of(lt + 256, bmN, bnN);
            AgN = A + (size_t)bmN * 256 * K;
            BgN = Bt + (size_t)bnN * 256 * K;
        }

        for (int it = 0; it < NT; ++it) {
            const int s = it & 1;
            const ushort_t* Ar = lds + ((s << 1) + wm) * 8192;
            const ushort_t* Br = lds + 32768 + ((s << 1) + (wn >> 1)) * 8192;
            const int itA = it + 1, itB = it + 2;
            const bool doA = (itA < NT) || hasN;
            const bool doB = (itB < NT) || hasN;
            const ushort_t* As = (itA < NT) ? Ag : AgN;
            const ushort_t* Bs = (itB < NT) ? Bg : BgN;
            const int kA = (itA & NTM) << 6;
            const int kB = (itB & NTM) << 6;
            const int soA = ((s ^ 1) << 1) * 16384;
            const int soB = 65536 + (s << 1) * 16384;

            // ---- phase 1
#pragma unroll
            for (int mi = 0; mi < 4; ++mi)
#pragma unroll
                for (int ks = 0; ks < 2; ++ks)
                    aF[mi * 2 + ks] = read_frag(Ar, mi * 16 + ra, ks * 32 + ca);
#pragma unroll
            for (int ni = 0; ni < 2; ++ni)
#pragma unroll
                for (int ks = 0; ks < 2; ++ks)
                    bF0[ni * 2 + ks] = read_frag(Br, rb + ni * 16 + ra, ks * 32 + ca);
            if (doA) STAGE(As, 0, kA, soA);
            BARRIER; LGKM0;
            __builtin_amdgcn_s_setprio(1);
            MFMA16(aF, 0, 0, bF0)
            __builtin_amdgcn_s_setprio(0);

            // ---- phase 2
#pragma unroll
            for (int ni = 0; ni < 2; ++ni)
#pragma unroll
                for (int ks = 0; ks < 2; ++ks)
                    bF1[ni * 2 + ks] = read_frag(Br, rb + 32 + ni * 16 + ra, ks * 32 + ca);
            if (doA) STAGE(As, 128, kA, soA + 16384);
            BARRIER; LGKM0;
            __builtin_amdgcn_s_setprio(1);
            MFMA16(aF, 0, 2, bF1)
            __builtin_amdgcn_s_setprio(0);

            // ---- phase 3
#pragma unroll
            for (int mi = 0; mi < 4; ++mi)
#pragma unroll
                for (int ks = 0; ks < 2; ++ks)
                    aG[mi * 2 + ks] = read_frag(Ar, 64 + mi * 16 + ra, ks * 32 + ca);
            BARRIER; LGKM0;
            if (doB) STAGE(Bs, 0, kB, soB);
            __builtin_amdgcn_s_setprio(1);
            MFMA16(aG, 4, 0, bF0)
            __builtin_amdgcn_s_setprio(0);

            // ---- phase 4
            if (doB) STAGE(Bs, 128, kB, soB + 16384);
            __builtin_amdgcn_s_setprio(1);
            MFMA16(aG, 4, 2, bF1)
            __builtin_amdgcn_s_setprio(0);
            if (doB) { VMCNT4; } else { VMCNT0; }
            BARRIER;
        }

        const int row0 = bm * 256 + wm * 128 + (lane >> 4) * 4;
        const int col0 = bn * 256 + wn * 64 + (lane & 15);
#pragma unroll
        for (int mi = 0; mi < 8; ++mi) {
#pragma unroll
            for (int ni = 0; ni < 4; ++ni) {
                const int col = col0 + ni * 16;
                f32x4 v = acc[mi][ni];
                if constexpr (F32OUT) {
                    float bz = bias[col];
                    float* C = (float*)Cc;
#pragma unroll
                    for (int q = 0; q < 4; ++q)
                        C[(size_t)(row0 + mi * 16 + q) * N + col] = v[q] + bz;
                } else {
                    ushort_t* C = (ushort_t*)Cc;
#pragma unroll
                    for (int q = 0; q < 4; ++q)
                        C[(size_t)(row0 + mi * 16 + q) * N + col] = f2bf(v[q]);
                }
                acc[mi][ni] = zf;
            }
        }
        Ag = AgN; Bg = BgN; bm = bmN; bn = bnN;
    }
}

// ---------------- merged prep (unchanged) ----------------
__global__ __launch_bounds__(256) void prep_kernel(const float* __restrict__ x,
                                                   ushort_t* __restrict__ x_bf,
                                                   const float* __restrict__ w_qkv,
                                                   ushort_t* __restrict__ wq_t,
                                                   const float* __restrict__ w_proj,
                                                   ushort_t* __restrict__ wp_t) {
    const int blk = blockIdx.x;
    const int t = threadIdx.x;
    if (blk < 2048) {
        const int n8 = 33554432 / 8;
        int i = blk * 256 + t;
        const int stride = 2048 * 256;
        for (; i < n8; i += stride) {
            const float4* p = (const float4*)(x + (size_t)i * 8);
            float4 a = p[0];
            float4 b = p[1];
            uint4 w;
            w.x = (unsigned)f2bf(a.x) | ((unsigned)f2bf(a.y) << 16);
            w.y = (unsigned)f2bf(a.z) | ((unsigned)f2bf(a.w) << 16);
            w.z = (unsigned)f2bf(b.x) | ((unsigned)f2bf(b.y) << 16);
            w.w = (unsigned)f2bf(b.z) | ((unsigned)f2bf(b.w) << 16);
            *(uint4*)(x_bf + (size_t)i * 8) = w;
        }
        return;
    }
    const float* in;
    ushort_t* out;
    int Cn, c0, r0;
    if (blk < 2048 + 768) {
        int id = blk - 2048;
        in = w_qkv; out = wq_t; Cn = 3072;
        c0 = (id % 48) * 64; r0 = (id / 48) * 64;
    } else {
        int id = blk - 2048 - 768;
        in = w_proj; out = wp_t; Cn = 1024;
        c0 = (id % 16) * 64; r0 = (id / 16) * 64;
    }
    __shared__ float tile[64][65];
    int lr = t >> 4;
    int lc = (t & 15) * 4;
#pragma unroll
    for (int i = 0; i < 4; i++) {
        const float* src = in + (size_t)(r0 + i * 16 + lr) * Cn + c0 + lc;
        float4 v = *(const float4*)src;
        tile[i * 16 + lr][lc + 0] = v.x;
        tile[i * 16 + lr][lc + 1] = v.y;
        tile[i * 16 + lr][lc + 2] = v.z;
        tile[i * 16 + lr][lc + 3] = v.w;
    }
    __syncthreads();
    int oc = t >> 4;
    int ok = (t & 15) * 4;
#pragma unroll
    for (int i = 0; i < 4; i++) {
        int c = c0 + i * 16 + oc;
        ushort4 w;
        w.x = f2bf(tile[ok + 0][i * 16 + oc]);
        w.y = f2bf(tile[ok + 1][i * 16 + oc]);
        w.z = f2bf(tile[ok + 2][i * 16 + oc]);
        w.w = f2bf(tile[ok + 3][i * 16 + oc]);
        *(ushort4*)(out + (size_t)c * 1024 + r0 + ok) = w;
    }
}

// ---------------- per-token head-mixing attention ----------------
// R11 vectorized V/O paths + R12: cross-token global-load prefetch (issue token
// it+1's 6 short8 loads BEFORE token it's LGKM0 memory-clobber, so HBM latency
// hides under softmax+PV) and trailing LGKM0 dropped (per-wave DS pipe is
// in-order => next-token ds_writes cannot pass this token's ds_reads).
__global__ __launch_bounds__(256) void attn_kernel(const ushort_t* __restrict__ qkv,
                                                   ushort_t* __restrict__ operm) {
    __shared__ __align__(16) ushort_t vtl[4][1024];   // 128 slots x 8 ushort / wave
    __shared__ __align__(16) float pl[4][16 * 20];
    __shared__ __align__(16) ushort_t oll[4][16 * 72];
    const int wave = threadIdx.x >> 6;
    const int lane = threadIdx.x & 63;
    ushort_t* VT = vtl[wave];
    float* P = pl[wave];
    ushort_t* OL = oll[wave];
    const int fr = lane & 15;
    const int hs = lane >> 4;
    const int fo = hs * 8;
    const int vg = lane & 15;
    const int vdq = lane >> 4;
    const int oh = lane >> 2;
    const int od = (lane & 3) * 16;
    const int tok0 = (blockIdx.x * 4 + wave) * 4;

    const ushort_t* row = qkv + (size_t)tok0 * 3072;
    short8 aq0 = *(const short8*)(row + fr * 64 + fo);
    short8 aq1 = *(const short8*)(row + fr * 64 + 32 + fo);
    short8 bk0 = *(const short8*)(row + 1024 + fr * 64 + fo);
    short8 bk1 = *(const short8*)(row + 1024 + fr * 64 + 32 + fo);
    short8 v0 = *(const short8*)(row + 2048 + vg * 64 + vdq * 16);
    short8 v1 = *(const short8*)(row + 2048 + vg * 64 + vdq * 16 + 8);

#pragma unroll
    for (int it = 0; it < 4; it++) {
        const int tok = tok0 + it;
        f32x4 s = {0.f, 0.f, 0.f, 0.f};
        s = __builtin_amdgcn_mfma_f32_16x16x32_bf16(aq0, bk0, s, 0, 0, 0);
        s = __builtin_amdgcn_mfma_f32_16x16x32_bf16(aq1, bk1, s, 0, 0, 0);
        // V -> VT (swizzled)
#pragma unroll
        for (int j = 0; j < 8; ++j) {
            int d = vdq * 16 + j;
            int slot = (2 * d + (vg >> 3)) ^ (2 * vdq);
            VT[slot * 8 + (vg & 7)] = (ushort_t)v0[j];
        }
#pragma unroll
        for (int j = 0; j < 8; ++j) {
            int d = vdq * 16 + 8 + j;
            int slot = (2 * d + (vg >> 3)) ^ (2 * vdq);
            VT[slot * 8 + (vg & 7)] = (ushort_t)v1[j];
        }
        float ls[4], m[4], p[4], sm[4];
#pragma unroll
        for (int q = 0; q < 4; q++) { ls[q] = s[q] * 0.125f; m[q] = ls[q]; }
#pragma unroll
        for (int d = 1; d < 16; d <<= 1)
#pragma unroll
            for (int q = 0; q < 4; q++) m[q] = fmaxf(m[q], __shfl_xor(m[q], d));
#pragma unroll
        for (int q = 0; q < 4; q++) { p[q] = __expf(ls[q] - m[q]); sm[q] = p[q]; }
#pragma unroll
        for (int d = 1; d < 16; d <<= 1)
#pragma unroll
            for (int q = 0; q < 4; q++) sm[q] += __shfl_xor(sm[q], d);
#pragma unroll
        for (int q = 0; q < 4; q++) P[(hs * 4 + q) * 20 + fr] = p[q];

        // ---- prefetch token it+1 BEFORE the lgkm drain (loads track vmcnt only;
        //      issued here so the clobber below cannot pin them after softmax)
        if (it < 3) {
            const ushort_t* rn = qkv + (size_t)(tok + 1) * 3072;
            aq0 = *(const short8*)(rn + fr * 64 + fo);
            aq1 = *(const short8*)(rn + fr * 64 + 32 + fo);
            bk0 = *(const short8*)(rn + 1024 + fr * 64 + fo);
            bk1 = *(const short8*)(rn + 1024 + fr * 64 + 32 + fo);
            v0  = *(const short8*)(rn + 2048 + vg * 64 + vdq * 16);
            v1  = *(const short8*)(rn + 2048 + vg * 64 + vdq * 16 + 8);
        }

        LGKM0;  // VT + P writes complete (wave-local; DS in-order per wave)
        short8 pa = {};
        short8 bv[4] = {};
        if (lane < 32) {
            const float* src = P + fr * 20 + fo;
            float4 r0 = *(const float4*)src;
            float4 r1 = *(const float4*)(src + 4);
            pa[0] = (short)f2bf(r0.x); pa[1] = (short)f2bf(r0.y);
            pa[2] = (short)f2bf(r0.z); pa[3] = (short)f2bf(r0.w);
            pa[4] = (short)f2bf(r1.x); pa[5] = (short)f2bf(r1.y);
            pa[6] = (short)f2bf(r1.z); pa[7] = (short)f2bf(r1.w);
#pragma unroll
            for (int db = 0; db < 4; ++db) {
                int d = db * 16 + fr;
                int slot = (2 * d + hs) ^ (2 * db);
                bv[db] = *(const short8*)(VT + slot * 8);
            }
        }
        f32x4 o[4] = {};
#pragma unroll
        for (int db = 0; db < 4; db++)
            o[db] = __builtin_amdgcn_mfma_f32_16x16x32_bf16(pa, bv[db], o[db], 0, 0, 0);
        float inv[4];
#pragma unroll
        for (int q = 0; q < 4; q++) inv[q] = 1.0f / sm[q];
#pragma unroll
        for (int db = 0; db < 4; db++)
#pragma unroll
            for (int q = 0; q < 4; q++)
                OL[(hs * 4 + q) * 72 + db * 16 + fr] = f2bf(o[db][q] * inv[q]);
        LGKM0;  // OL writes complete
        int b = tok >> 12;
        int n = tok & 4095;
        short8 w0 = *(const short8*)(OL + oh * 72 + od);
        short8 w1 = *(const short8*)(OL + oh * 72 + od + 8);
        ushort_t* dst = operm + ((size_t)b << 22)
                      + ((size_t)(oh * 256 + (n >> 4))) * 1024 + (n & 15) * 64 + od;
        *(short8*)dst = w0;
        *(short8*)(dst + 8) = w1;
        // no trailing drain: per-wave in-order DS pipe orders next-token writes
        // after this token's OL/VT reads (WAR safe)
    }
}

extern "C" void kernel_launch(void* const* d_in, const int* in_sizes, int n_in,
                              void* d_out, int out_size, void* d_ws, size_t ws_size,
                              hipStream_t stream) {
    const float* x = (const float*)d_in[0];
    const float* w_qkv = (const float*)d_in[1];
    const float* w_proj = (const float*)d_in[2];
    const float* b_proj = (const float*)d_in[3];
    float* out = (float*)d_out;

    char* ws = (char*)d_ws;
    ushort_t* x_bf  = (ushort_t*)(ws);                  //  64 MiB: [32768][1024]
    ushort_t* wq_t  = (ushort_t*)(ws + 67108864);       //   6 MiB: [3072][1024]
    ushort_t* wp_t  = (ushort_t*)(ws + 73400320);       //   2 MiB: [1024][1024]
    ushort_t* qkv   = (ushort_t*)(ws + 75497472);       // 192 MiB: [32768][3072]
    ushort_t* operm = (ushort_t*)(ws + 276824064);      //  64 MiB: [32768][1024]

    prep_kernel<<<3072, 256, 0, stream>>>(x, x_bf, w_qkv, wq_t, w_proj, wp_t);
    gemm256<0><<<256, 512, 0, stream>>>(x_bf, wq_t, qkv, nullptr, 3072, 1024, 12, 1536);
    attn_kernel<<<2048, 256, 0, stream>>>(qkv, operm);
    gemm256<1><<<256, 512, 0, stream>>>(operm, wp_t, out, b_proj, 1024, 1024, 4, 512);
}